// Round 11
// baseline (123.376 us; speedup 1.0000x reference)
//
#include <hip/hip_runtime.h>
#include <hip/hip_bf16.h>

#define TPB 256
#define BATCH 262144
#define S 34   // LDS row stride in dwords

typedef __fp16   fp16x2  __attribute__((ext_vector_type(2)));
typedef _Float16 half8_t __attribute__((ext_vector_type(8)));
typedef float    f32x4   __attribute__((ext_vector_type(4)));

#define WAVE_LDS_FENCE() asm volatile("s_waitcnt lgkmcnt(0)" ::: "memory")

__device__ __forceinline__ float fast_tanh(float x) {
    float ax = fabsf(x);
    float e  = __expf(-2.0f * ax);
    float t  = (1.0f - e) * __builtin_amdgcn_rcpf(1.0f + e);
    return copysignf(t, x);
}

template <int MASK>
__device__ __forceinline__ void ry_gate(float* psi, float c, float s) {
#pragma unroll
    for (int i = 0; i < 16; i++) {
        if (!(i & MASK)) {
            float a = psi[i], b = psi[i | MASK];
            psi[i]        = c * a - s * b;
            psi[i | MASK] = s * a + c * b;
        }
    }
}

template <int CM, int TM>
__device__ __forceinline__ void cnot_gate(float* psi) {
#pragma unroll
    for (int i = 0; i < 16; i++) {
        if ((i & CM) && !(i & TM)) {
            float t = psi[i];
            psi[i] = psi[i | TM];
            psi[i | TM] = t;
        }
    }
}

__device__ __forceinline__ half8_t cvt8(float4 a, float4 b) {
    fp16x2 p0 = __builtin_amdgcn_cvt_pkrtz(a.x, a.y);
    fp16x2 p1 = __builtin_amdgcn_cvt_pkrtz(a.z, a.w);
    fp16x2 p2 = __builtin_amdgcn_cvt_pkrtz(b.x, b.y);
    fp16x2 p3 = __builtin_amdgcn_cvt_pkrtz(b.z, b.w);
    half8_t r;
    r[0] = (_Float16)p0[0]; r[1] = (_Float16)p0[1];
    r[2] = (_Float16)p1[0]; r[3] = (_Float16)p1[1];
    r[4] = (_Float16)p2[0]; r[5] = (_Float16)p2[1];
    r[6] = (_Float16)p3[0]; r[7] = (_Float16)p3[1];
    return r;
}

// 32 rows per wave: 2 MFMA m-tiles; middle on lanes 0-31 (one row/lane).
// 2048 blocks x 4 waves = 8192 waves -> staggered generations + 6 waves/SIMD.
__global__ __launch_bounds__(TPB, 6) void qnet_kernel(
    const float* __restrict__ state,
    const float* __restrict__ W1, const float* __restrict__ b1,
    const float* __restrict__ W2, const float* __restrict__ b2,
    const float* __restrict__ qp,
    const float* __restrict__ H1, const float* __restrict__ c1,
    const float* __restrict__ H2, const float* __restrict__ c2,
    float* __restrict__ out)
{
    __shared__ float sh[4 * 32 * S];   // one 32-row slice per wave (17408 B)
    __shared__ float sQc[8], sQs[8];

    const int tid  = threadIdx.x;
    const int lane = tid & 63;
    const int wv   = tid >> 6;
    const int l15  = lane & 15;
    const int lq   = lane >> 4;
    const int rowBase = blockIdx.x * 128 + wv * 32;
    float* hb = sh + wv * 32 * S;

    // ---- stage uniform qp sin/cos once per block ----
    if (tid < 8) {
        float s, c;
        __sincosf(0.5f * qp[tid], &s, &c);
        sQs[tid] = s; sQc[tid] = c;
    }
    __syncthreads();

    // ---- A fragments: convert to fp16 on arrival (keep only 16 VGPRs) ----
    half8_t aX[2][2];
#pragma unroll
    for (int mt = 0; mt < 2; mt++) {
        const float* p0 = state + (size_t)(rowBase + 16 * mt + l15) * 64 + lq * 8;
#pragma unroll
        for (int kt = 0; kt < 2; kt++)
            aX[mt][kt] = cvt8(*(const float4*)(p0 + 32 * kt),
                              *(const float4*)(p0 + 32 * kt + 4));
    }

    // ---- B-fragments of W1 (B[k][n] = W1[n*64+k]) ----
    half8_t bW1[2][2];
#pragma unroll
    for (int u = 0; u < 2; u++)
#pragma unroll
        for (int kt = 0; kt < 2; kt++) {
            const float* p = W1 + (16 * u + l15) * 64 + 32 * kt + lq * 8;
            bW1[u][kt] = cvt8(*(const float4*)p, *(const float4*)(p + 4));
        }
    const float bias0 = b1[l15];
    const float bias1 = b1[16 + l15];

    // ---- Layer 1 via MFMA ----
    f32x4 acc[2][2];
#pragma unroll
    for (int mt = 0; mt < 2; mt++)
#pragma unroll
        for (int u = 0; u < 2; u++)
#pragma unroll
            for (int r = 0; r < 4; r++) acc[mt][u][r] = 0.0f;

#pragma unroll
    for (int kt = 0; kt < 2; kt++)
#pragma unroll
        for (int mt = 0; mt < 2; mt++) {
            acc[mt][0] = __builtin_amdgcn_mfma_f32_16x16x32_f16(aX[mt][kt], bW1[0][kt], acc[mt][0], 0, 0, 0);
            acc[mt][1] = __builtin_amdgcn_mfma_f32_16x16x32_f16(aX[mt][kt], bW1[1][kt], acc[mt][1], 0, 0, 0);
        }

    // ---- h = relu(acc + b1) -> LDS (C layout: row=16mt+4lq+r, col=16u+l15) ----
#pragma unroll
    for (int mt = 0; mt < 2; mt++)
#pragma unroll
        for (int r = 0; r < 4; r++) {
            int row = 16 * mt + 4 * lq + r;
            hb[row * S + l15]      = fmaxf(acc[mt][0][r] + bias0, 0.0f);
            hb[row * S + 16 + l15] = fmaxf(acc[mt][1][r] + bias1, 0.0f);
        }
    WAVE_LDS_FENCE();

    // ---- per-row middle on lanes 0-31 ----
    if (lane < 32) {
        float h[32];
        const float2* hr = reinterpret_cast<const float2*>(hb + lane * S);
#pragma unroll
        for (int j = 0; j < 16; j++) { float2 v = hr[j]; h[2 * j] = v.x; h[2 * j + 1] = v.y; }

        float e[4];
#pragma unroll
        for (int w = 0; w < 4; w++) {
            float a = b2[w];
#pragma unroll
            for (int k = 0; k < 32; k++) a = fmaf(h[k], W2[w * 32 + k], a);
            e[w] = fast_tanh(a);
        }

        float psi[16];
#pragma unroll
        for (int i = 0; i < 16; i++) psi[i] = 0.0f;
        psi[0] = 1.0f;

        float s, c;
        __sincosf(0.5f * e[0], &s, &c); ry_gate<8>(psi, c, s);
        __sincosf(0.5f * e[1], &s, &c); ry_gate<4>(psi, c, s);
        __sincosf(0.5f * e[2], &s, &c); ry_gate<2>(psi, c, s);
        __sincosf(0.5f * e[3], &s, &c); ry_gate<1>(psi, c, s);

#pragma unroll
        for (int layer = 0; layer < 2; layer++) {
            cnot_gate<8, 4>(psi);
            cnot_gate<4, 2>(psi);
            cnot_gate<2, 1>(psi);
            cnot_gate<1, 8>(psi);
            ry_gate<8>(psi, sQc[layer * 4 + 0], sQs[layer * 4 + 0]);
            ry_gate<4>(psi, sQc[layer * 4 + 1], sQs[layer * 4 + 1]);
            ry_gate<2>(psi, sQc[layer * 4 + 2], sQs[layer * 4 + 2]);
            ry_gate<1>(psi, sQc[layer * 4 + 3], sQs[layer * 4 + 3]);
        }

        float p[16];
#pragma unroll
        for (int i = 0; i < 16; i++) p[i] = psi[i] * psi[i];
        float qf[4];
#pragma unroll
        for (int w = 0; w < 4; w++) {
            const int m = 8 >> w;
            float z = 0.0f;
#pragma unroll
            for (int i = 0; i < 16; i++) z += (i & m) ? -p[i] : p[i];
            qf[w] = z;
        }

        // h2 = relu(qf @ H1^T + c1), streamed straight into LDS (h row is consumed)
        float2* hw = reinterpret_cast<float2*>(hb + lane * S);
#pragma unroll
        for (int jj = 0; jj < 16; jj++) {
            float a0 = c1[2 * jj], a1 = c1[2 * jj + 1];
            a0 = fmaf(qf[0], H1[(2 * jj) * 4 + 0], a0);
            a0 = fmaf(qf[1], H1[(2 * jj) * 4 + 1], a0);
            a0 = fmaf(qf[2], H1[(2 * jj) * 4 + 2], a0);
            a0 = fmaf(qf[3], H1[(2 * jj) * 4 + 3], a0);
            a1 = fmaf(qf[0], H1[(2 * jj + 1) * 4 + 0], a1);
            a1 = fmaf(qf[1], H1[(2 * jj + 1) * 4 + 1], a1);
            a1 = fmaf(qf[2], H1[(2 * jj + 1) * 4 + 2], a1);
            a1 = fmaf(qf[3], H1[(2 * jj + 1) * 4 + 3], a1);
            hw[jj] = make_float2(fmaxf(a0, 0.0f), fmaxf(a1, 0.0f));
        }
    }
    WAVE_LDS_FENCE();   // same-wave DS queue is in-order; wait for h2 writes

    // ---- H2 layer via MFMA: B[k][n] = H2[n*32+k], N=16 ----
    half8_t bH2;
    {
        const float* p = H2 + l15 * 32 + lq * 8;
        bH2 = cvt8(*(const float4*)p, *(const float4*)(p + 4));
    }

    f32x4 acc2[2];
#pragma unroll
    for (int mt = 0; mt < 2; mt++)
#pragma unroll
        for (int r = 0; r < 4; r++) acc2[mt][r] = 0.0f;

#pragma unroll
    for (int mt = 0; mt < 2; mt++) {
        const float2* q = reinterpret_cast<const float2*>(hb + (16 * mt + l15) * S + lq * 8);
        float2 a0 = q[0], a1 = q[1], a2 = q[2], a3 = q[3];
        half8_t a = cvt8(make_float4(a0.x, a0.y, a1.x, a1.y),
                         make_float4(a2.x, a2.y, a3.x, a3.y));
        acc2[mt] = __builtin_amdgcn_mfma_f32_16x16x32_f16(a, bH2, acc2[mt], 0, 0, 0);
    }

    // ---- epilogue ----
    const float cc = c2[l15];
#pragma unroll
    for (int mt = 0; mt < 2; mt++)
#pragma unroll
        for (int r = 0; r < 4; r++) {
            int row = rowBase + 16 * mt + 4 * lq + r;
            out[(size_t)row * 16 + l15] = fast_tanh(acc2[mt][r] + cc);
        }
}

extern "C" void kernel_launch(void* const* d_in, const int* in_sizes, int n_in,
                              void* d_out, int out_size, void* d_ws, size_t ws_size,
                              hipStream_t stream) {
    const float* state = (const float*)d_in[0];
    const float* W1    = (const float*)d_in[1];
    const float* b1    = (const float*)d_in[2];
    const float* W2    = (const float*)d_in[3];
    const float* b2    = (const float*)d_in[4];
    const float* qp    = (const float*)d_in[5];
    const float* H1    = (const float*)d_in[6];
    const float* c1    = (const float*)d_in[7];
    const float* H2    = (const float*)d_in[8];
    const float* c2    = (const float*)d_in[9];
    float* out = (float*)d_out;

    const int blocks = BATCH / 128;   // 2048 blocks, 8192 waves
    qnet_kernel<<<blocks, TPB, 0, stream>>>(state, W1, b1, W2, b2, qp,
                                            H1, c1, H2, c2, out);
}

// Round 12
// 121.336 us; speedup vs baseline: 1.0168x; 1.0168x over previous
//
#include <hip/hip_runtime.h>
#include <hip/hip_bf16.h>

#define TPB 256
#define BATCH 262144
#define S 34   // LDS row stride in dwords (even -> 8B rows, <=2-way bank aliasing)

typedef __fp16   fp16x2  __attribute__((ext_vector_type(2)));   // cvt_pkrtz result type
typedef _Float16 half8_t __attribute__((ext_vector_type(8)));
typedef float    f32x4   __attribute__((ext_vector_type(4)));

// Intra-wave LDS fence: LDS slices are per-wave, so no block barrier needed.
#define WAVE_LDS_FENCE() asm volatile("s_waitcnt lgkmcnt(0)" ::: "memory")

__device__ __forceinline__ float fast_tanh(float x) {
    float ax = fabsf(x);
    float e  = __expf(-2.0f * ax);
    float t  = (1.0f - e) * __builtin_amdgcn_rcpf(1.0f + e);
    return copysignf(t, x);
}

template <int MASK>
__device__ __forceinline__ void ry_gate(float* psi, float c, float s) {
#pragma unroll
    for (int i = 0; i < 16; i++) {
        if (!(i & MASK)) {
            float a = psi[i], b = psi[i | MASK];
            psi[i]        = c * a - s * b;
            psi[i | MASK] = s * a + c * b;
        }
    }
}

template <int CM, int TM>
__device__ __forceinline__ void cnot_gate(float* psi) {
#pragma unroll
    for (int i = 0; i < 16; i++) {
        if ((i & CM) && !(i & TM)) {
            float t = psi[i];
            psi[i] = psi[i | TM];
            psi[i | TM] = t;
        }
    }
}

__device__ __forceinline__ half8_t cvt8(float4 a, float4 b) {
    fp16x2 p0 = __builtin_amdgcn_cvt_pkrtz(a.x, a.y);
    fp16x2 p1 = __builtin_amdgcn_cvt_pkrtz(a.z, a.w);
    fp16x2 p2 = __builtin_amdgcn_cvt_pkrtz(b.x, b.y);
    fp16x2 p3 = __builtin_amdgcn_cvt_pkrtz(b.z, b.w);
    half8_t r;
    r[0] = (_Float16)p0[0]; r[1] = (_Float16)p0[1];
    r[2] = (_Float16)p1[0]; r[3] = (_Float16)p1[1];
    r[4] = (_Float16)p2[0]; r[5] = (_Float16)p2[1];
    r[6] = (_Float16)p3[0]; r[7] = (_Float16)p3[1];
    return r;
}

__global__ __launch_bounds__(TPB, 4) void qnet_kernel(
    const float* __restrict__ state,
    const float* __restrict__ W1, const float* __restrict__ b1,
    const float* __restrict__ W2, const float* __restrict__ b2,
    const float* __restrict__ qp,
    const float* __restrict__ H1, const float* __restrict__ c1,
    const float* __restrict__ H2, const float* __restrict__ c2,
    float* __restrict__ out)
{
    __shared__ float sh[4 * 64 * S];   // one 64xS slice per wave

    const int tid  = threadIdx.x;
    const int lane = tid & 63;
    const int wv   = tid >> 6;
    const int l15  = lane & 15;
    const int lq   = lane >> 4;
    const int rowBase = blockIdx.x * TPB + wv * 64;
    float* hb = sh + wv * 64 * S;

    // ---- PHASE SKEW: de-align the grid-wide load convoy. Wave-uniform
    // branch; cohorts start ~0/1.1/2.1/3.2 us apart so one cohort computes
    // while the next cohort's HBM loads drain (s_sleep imm is 7-bit,
    // 64*imm clocks). ----
    {
        const int ph = (blockIdx.x + wv) & 3;
        if (ph == 1)      __builtin_amdgcn_s_sleep(40);
        else if (ph == 2) __builtin_amdgcn_s_sleep(80);
        else if (ph == 3) __builtin_amdgcn_s_sleep(120);
    }

    // ---- PREFETCH: issue all 8 state loads first (A fragments) ----
    float4 xa[4][2], xb[4][2];   // [mt][kt]
#pragma unroll
    for (int mt = 0; mt < 4; mt++) {
        const float* p0 = state + (size_t)(rowBase + 16 * mt + l15) * 64 + lq * 8;
#pragma unroll
        for (int kt = 0; kt < 2; kt++) {
            xa[mt][kt] = *(const float4*)(p0 + 32 * kt);
            xb[mt][kt] = *(const float4*)(p0 + 32 * kt + 4);
        }
    }

    // ---- B-fragments of W1 (B[k][n] = W1[n*64+k]) ----
    half8_t bW1[2][2];
#pragma unroll
    for (int u = 0; u < 2; u++)
#pragma unroll
        for (int kt = 0; kt < 2; kt++) {
            const float* p = W1 + (16 * u + l15) * 64 + 32 * kt + lq * 8;
            bW1[u][kt] = cvt8(*(const float4*)p, *(const float4*)(p + 4));
        }
    const float bias0 = b1[l15];
    const float bias1 = b1[16 + l15];

    // ---- Layer 1 via MFMA ----
    f32x4 acc[4][2];
#pragma unroll
    for (int mt = 0; mt < 4; mt++)
#pragma unroll
        for (int u = 0; u < 2; u++)
#pragma unroll
            for (int r = 0; r < 4; r++) acc[mt][u][r] = 0.0f;

#pragma unroll
    for (int kt = 0; kt < 2; kt++) {
#pragma unroll
        for (int mt = 0; mt < 4; mt++) {
            half8_t a = cvt8(xa[mt][kt], xb[mt][kt]);
            acc[mt][0] = __builtin_amdgcn_mfma_f32_16x16x32_f16(a, bW1[0][kt], acc[mt][0], 0, 0, 0);
            acc[mt][1] = __builtin_amdgcn_mfma_f32_16x16x32_f16(a, bW1[1][kt], acc[mt][1], 0, 0, 0);
        }
    }

    // ---- h = relu(acc + b1) -> LDS (C layout: row=16mt+4lq+r, col=16u+l15) ----
#pragma unroll
    for (int mt = 0; mt < 4; mt++)
#pragma unroll
        for (int r = 0; r < 4; r++) {
            int row = 16 * mt + 4 * lq + r;
            hb[row * S + l15]      = fmaxf(acc[mt][0][r] + bias0, 0.0f);
            hb[row * S + 16 + l15] = fmaxf(acc[mt][1][r] + bias1, 0.0f);
        }
    WAVE_LDS_FENCE();

    // ---- per-thread middle: my row = lane ----
    float h[32];
    {
        const float2* hr = reinterpret_cast<const float2*>(hb + lane * S);
#pragma unroll
        for (int j = 0; j < 16; j++) { float2 v = hr[j]; h[2 * j] = v.x; h[2 * j + 1] = v.y; }
    }

    float e[4];
#pragma unroll
    for (int w = 0; w < 4; w++) {
        float a = b2[w];
#pragma unroll
        for (int k = 0; k < 32; k++) a = fmaf(h[k], W2[w * 32 + k], a);
        e[w] = fast_tanh(a);
    }

    float qf[4];
    {
        float psi[16];
#pragma unroll
        for (int i = 0; i < 16; i++) psi[i] = 0.0f;
        psi[0] = 1.0f;

        float s, c;
        __sincosf(0.5f * e[0], &s, &c); ry_gate<8>(psi, c, s);
        __sincosf(0.5f * e[1], &s, &c); ry_gate<4>(psi, c, s);
        __sincosf(0.5f * e[2], &s, &c); ry_gate<2>(psi, c, s);
        __sincosf(0.5f * e[3], &s, &c); ry_gate<1>(psi, c, s);

#pragma unroll
        for (int layer = 0; layer < 2; layer++) {
            cnot_gate<8, 4>(psi);
            cnot_gate<4, 2>(psi);
            cnot_gate<2, 1>(psi);
            cnot_gate<1, 8>(psi);
#pragma unroll
            for (int i = 0; i < 4; i++) {
                float s2, c2v;
                __sincosf(0.5f * qp[layer * 4 + i], &s2, &c2v);
                if (i == 0) ry_gate<8>(psi, c2v, s2);
                if (i == 1) ry_gate<4>(psi, c2v, s2);
                if (i == 2) ry_gate<2>(psi, c2v, s2);
                if (i == 3) ry_gate<1>(psi, c2v, s2);
            }
        }

        float p[16];
#pragma unroll
        for (int i = 0; i < 16; i++) p[i] = psi[i] * psi[i];
#pragma unroll
        for (int w = 0; w < 4; w++) {
            const int m = 8 >> w;
            float z = 0.0f;
#pragma unroll
            for (int i = 0; i < 16; i++) z += (i & m) ? -p[i] : p[i];
            qf[w] = z;
        }
    }

    float h2[32];
#pragma unroll
    for (int j = 0; j < 32; j++) {
        float a = c1[j];
        a = fmaf(qf[0], H1[j * 4 + 0], a);
        a = fmaf(qf[1], H1[j * 4 + 1], a);
        a = fmaf(qf[2], H1[j * 4 + 2], a);
        a = fmaf(qf[3], H1[j * 4 + 3], a);
        h2[j] = fmaxf(a, 0.0f);
    }

    WAVE_LDS_FENCE();   // all h reads done; reuse buffer for h2
    {
        float2* hw = reinterpret_cast<float2*>(hb + lane * S);
#pragma unroll
        for (int j = 0; j < 16; j++) hw[j] = make_float2(h2[2 * j], h2[2 * j + 1]);
    }
    WAVE_LDS_FENCE();

    // ---- H2 layer via MFMA: B[k][n] = H2[n*32+k], N=16 ----
    half8_t bH2;
    {
        const float* p = H2 + l15 * 32 + lq * 8;
        bH2 = cvt8(*(const float4*)p, *(const float4*)(p + 4));
    }

    f32x4 acc2[4];
#pragma unroll
    for (int mt = 0; mt < 4; mt++)
#pragma unroll
        for (int r = 0; r < 4; r++) acc2[mt][r] = 0.0f;

#pragma unroll
    for (int mt = 0; mt < 4; mt++) {
        const float2* q = reinterpret_cast<const float2*>(hb + (16 * mt + l15) * S + lq * 8);
        float2 a0 = q[0], a1 = q[1], a2 = q[2], a3 = q[3];
        half8_t a = cvt8(make_float4(a0.x, a0.y, a1.x, a1.y),
                         make_float4(a2.x, a2.y, a3.x, a3.y));
        acc2[mt] = __builtin_amdgcn_mfma_f32_16x16x32_f16(a, bH2, acc2[mt], 0, 0, 0);
    }

    // ---- epilogue ----
    const float cc = c2[l15];
#pragma unroll
    for (int mt = 0; mt < 4; mt++)
#pragma unroll
        for (int r = 0; r < 4; r++) {
            int row = rowBase + 16 * mt + 4 * lq + r;
            out[(size_t)row * 16 + l15] = fast_tanh(acc2[mt][r] + cc);
        }
}

extern "C" void kernel_launch(void* const* d_in, const int* in_sizes, int n_in,
                              void* d_out, int out_size, void* d_ws, size_t ws_size,
                              hipStream_t stream) {
    const float* state = (const float*)d_in[0];
    const float* W1    = (const float*)d_in[1];
    const float* b1    = (const float*)d_in[2];
    const float* W2    = (const float*)d_in[3];
    const float* b2    = (const float*)d_in[4];
    const float* qp    = (const float*)d_in[5];
    const float* H1    = (const float*)d_in[6];
    const float* c1    = (const float*)d_in[7];
    const float* H2    = (const float*)d_in[8];
    const float* c2    = (const float*)d_in[9];
    float* out = (float*)d_out;

    const int blocks = BATCH / TPB;   // 1024
    qnet_kernel<<<blocks, TPB, 0, stream>>>(state, W1, b1, W2, b2, qp,
                                            H1, c1, H2, c2, out);
}